// Round 1
// baseline (43.532 us; speedup 1.0000x reference)
//
#include <hip/hip_runtime.h>
#include <math.h>

#define VOCAB 100000
#define DIM 128
#define BATCH 16384
#define CTX 10
#define NEG 10

// Numerically stable log_sigmoid(x) = min(x,0) - log1p(exp(-|x|))
__device__ __forceinline__ float log_sigmoid_f(float x) {
    return fminf(x, 0.0f) - log1pf(expf(-fabsf(x)));
}

__device__ __forceinline__ float wave_reduce_sum(float v) {
    #pragma unroll
    for (int off = 32; off > 0; off >>= 1)
        v += __shfl_xor(v, off, 64);
    return v;
}

// One wave (64 lanes) per batch element; lane owns a float2 (2 dims of D=128).
// 4 waves per 256-thread block -> 4 batch elements per block.
__global__ __launch_bounds__(256) void cbow_main(
    const float* __restrict__ W_embed, const float* __restrict__ W_out,
    const int* __restrict__ ctx_ids, const int* __restrict__ tgt_ids,
    const int* __restrict__ neg_ids, float* __restrict__ partial)
{
    const int wave = threadIdx.x >> 6;
    const int lane = threadIdx.x & 63;
    const int b = blockIdx.x * 4 + wave;

    const float2* __restrict__ We = (const float2*)W_embed;
    const float2* __restrict__ Wo = (const float2*)W_out;

    // context mean: sum 10 gathered rows, each row = 64 float2 (one per lane)
    float2 acc = make_float2(0.0f, 0.0f);
    #pragma unroll
    for (int j = 0; j < CTX; ++j) {
        const int row = ctx_ids[b * CTX + j];      // wave-uniform -> s_load
        const float2 v = We[(size_t)row * 64 + lane];
        acc.x += v.x; acc.y += v.y;
    }
    const float2 mean = make_float2(acc.x * 0.1f, acc.y * 0.1f);

    float loss = 0.0f;
    {
        const int row = tgt_ids[b];
        const float2 t = Wo[(size_t)row * 64 + lane];
        const float s = wave_reduce_sum(mean.x * t.x + mean.y * t.y);
        loss += log_sigmoid_f(s);
    }
    #pragma unroll
    for (int n = 0; n < NEG; ++n) {
        const int row = neg_ids[b * NEG + n];
        const float2 v = Wo[(size_t)row * 64 + lane];
        const float s = wave_reduce_sum(mean.x * v.x + mean.y * v.y);
        loss += log_sigmoid_f(-s);
    }

    __shared__ float lsum[4];
    if (lane == 0) lsum[wave] = loss;
    __syncthreads();
    if (threadIdx.x == 0)
        partial[blockIdx.x] = (lsum[0] + lsum[1]) + (lsum[2] + lsum[3]);
}

// Deterministic fixed-order reduction of the 4096 block partials.
__global__ __launch_bounds__(256) void cbow_reduce(
    const float* __restrict__ partial, float* __restrict__ out)
{
    __shared__ float s[256];
    float v = 0.0f;
    #pragma unroll
    for (int k = 0; k < 16; ++k)
        v += partial[threadIdx.x + 256 * k];
    s[threadIdx.x] = v;
    __syncthreads();
    for (int stride = 128; stride > 0; stride >>= 1) {
        if (threadIdx.x < stride) s[threadIdx.x] += s[threadIdx.x + stride];
        __syncthreads();
    }
    if (threadIdx.x == 0) out[0] = -s[0] / (float)BATCH;
}

extern "C" void kernel_launch(void* const* d_in, const int* in_sizes, int n_in,
                              void* d_out, int out_size, void* d_ws, size_t ws_size,
                              hipStream_t stream) {
    const float* W_embed = (const float*)d_in[0];
    const float* W_out   = (const float*)d_in[1];
    const int* ctx_ids   = (const int*)d_in[2];
    const int* tgt_ids   = (const int*)d_in[3];
    const int* neg_ids   = (const int*)d_in[4];
    float* out = (float*)d_out;
    float* partial = (float*)d_ws;   // 4096 floats, fully rewritten each call

    cbow_main<<<BATCH / 4, 256, 0, stream>>>(W_embed, W_out, ctx_ids, tgt_ids,
                                             neg_ids, partial);
    cbow_reduce<<<1, 256, 0, stream>>>(partial, out);
}

// Round 2
// 33.201 us; speedup vs baseline: 1.3112x; 1.3112x over previous
//
#include <hip/hip_runtime.h>
#include <math.h>

#define VOCAB 100000
#define DIM 128
#define BATCH 16384
#define CTX 10
#define NEG 10
#define NSCORE (NEG + 1)

// Fast, accurate-enough log_sigmoid(x) = min(x,0) - log(1 + exp(-|x|)).
// __expf/__logf -> v_exp_f32/v_log_f32 (~1 ulp); error averages out over
// the 180k-term mean.
__device__ __forceinline__ float log_sigmoid_f(float x) {
    const float e = __expf(-fabsf(x));
    return fminf(x, 0.0f) - __logf(1.0f + e);
}

// One wave handles TWO batch elements: lanes 0-31 -> b0, lanes 32-63 -> b1.
// Each 32-lane half owns a full D=128 row as float4 per lane.
// 4 waves/block (256 threads) -> 8 batch elements per block -> 2048 blocks.
__global__ __launch_bounds__(256) void cbow_main(
    const float* __restrict__ W_embed, const float* __restrict__ W_out,
    const int* __restrict__ ctx_ids, const int* __restrict__ tgt_ids,
    const int* __restrict__ neg_ids, float* __restrict__ partial)
{
    const int wave = threadIdx.x >> 6;
    const int lane = threadIdx.x & 63;
    const int half = lane >> 5;          // which batch element in this wave
    const int l32  = lane & 31;          // lane within the 32-lane row
    const int b = blockIdx.x * 8 + wave * 2 + half;

    const float4* __restrict__ We = (const float4*)W_embed;
    const float4* __restrict__ Wo = (const float4*)W_out;

    // --- context mean: 10 gathered rows, each row = 32 float4 ---
    float mx = 0.f, my = 0.f, mz = 0.f, mw = 0.f;
    #pragma unroll
    for (int j = 0; j < CTX; ++j) {
        const int row = ctx_ids[b * CTX + j];   // uniform per half-wave
        const float4 v = We[(size_t)row * 32 + l32];
        mx += v.x; my += v.y; mz += v.z; mw += v.w;
    }
    mx *= 0.1f; my *= 0.1f; mz *= 0.1f; mw *= 0.1f;

    // --- 11 per-lane partial dots (target + 10 negatives) ---
    float p[NSCORE];
    #pragma unroll
    for (int n = 0; n < NSCORE; ++n) {
        const int row = (n == 0) ? tgt_ids[b] : neg_ids[b * NEG + (n - 1)];
        const float4 v = Wo[(size_t)row * 32 + l32];
        p[n] = mx * v.x + my * v.y + mz * v.z + mw * v.w;
    }

    // --- 11 independent 5-level butterflies (within each 32-lane half),
    //     interleaved level-by-level for ILP ---
    #pragma unroll
    for (int off = 16; off >= 1; off >>= 1) {
        #pragma unroll
        for (int n = 0; n < NSCORE; ++n)
            p[n] += __shfl_xor(p[n], off, 64);
    }

    // every lane of a half now holds its element's full scores
    float loss = log_sigmoid_f(p[0]);
    #pragma unroll
    for (int n = 1; n < NSCORE; ++n)
        loss += log_sigmoid_f(-p[n]);

    __shared__ float lsum[8];
    if (l32 == 0) lsum[wave * 2 + half] = loss;
    __syncthreads();
    if (threadIdx.x == 0) {
        float s = 0.f;
        #pragma unroll
        for (int i = 0; i < 8; ++i) s += lsum[i];
        partial[blockIdx.x] = s;
    }
}

// Deterministic fixed-order reduction of the 2048 block partials.
__global__ __launch_bounds__(256) void cbow_reduce(
    const float* __restrict__ partial, float* __restrict__ out)
{
    __shared__ float s[256];
    float v = 0.0f;
    #pragma unroll
    for (int k = 0; k < 8; ++k)
        v += partial[threadIdx.x + 256 * k];
    s[threadIdx.x] = v;
    __syncthreads();
    for (int stride = 128; stride > 0; stride >>= 1) {
        if (threadIdx.x < stride) s[threadIdx.x] += s[threadIdx.x + stride];
        __syncthreads();
    }
    if (threadIdx.x == 0) out[0] = -s[0] / (float)BATCH;
}

extern "C" void kernel_launch(void* const* d_in, const int* in_sizes, int n_in,
                              void* d_out, int out_size, void* d_ws, size_t ws_size,
                              hipStream_t stream) {
    const float* W_embed = (const float*)d_in[0];
    const float* W_out   = (const float*)d_in[1];
    const int* ctx_ids   = (const int*)d_in[2];
    const int* tgt_ids   = (const int*)d_in[3];
    const int* neg_ids   = (const int*)d_in[4];
    float* out = (float*)d_out;
    float* partial = (float*)d_ws;   // 2048 floats, fully rewritten each call

    cbow_main<<<BATCH / 8, 256, 0, stream>>>(W_embed, W_out, ctx_ids, tgt_ids,
                                             neg_ids, partial);
    cbow_reduce<<<1, 256, 0, stream>>>(partial, out);
}